// Round 15
// baseline (193.725 us; speedup 1.0000x reference)
//
#include <hip/hip_runtime.h>
#include <hip/hip_bf16.h>

#define NN 8192
#define KIN 512
#define KOUT 256
#define ALPHA 0.2f
#define BK 64
#define ROWS 128        // rows per block
#define KQ (NN / 4)     // k-range per quarter
#define NT4 (KQ / BK)   // 32 k-tiles per quarter

typedef __bf16 bf16x8 __attribute__((ext_vector_type(8)));
typedef float f32x4 __attribute__((ext_vector_type(4)));
typedef unsigned short ushort8_t __attribute__((ext_vector_type(8)));
typedef unsigned short ushort4_t __attribute__((ext_vector_type(4)));
typedef int int4v __attribute__((ext_vector_type(4)));

__device__ __forceinline__ float lrelu(float x) { return x > 0.f ? x : ALPHA * x; }

__device__ __forceinline__ unsigned short f2bf(float f) {
  union { float f; unsigned u; } v; v.f = f;
  unsigned r = v.u + 0x7fffu + ((v.u >> 16) & 1u);  // RNE to bf16
  return (unsigned short)(r >> 16);
}

// pack two f32 -> one u32 of 2x bf16 (RNE) via HW instruction
__device__ __forceinline__ unsigned cvt_pk_bf16(float lo, float hi) {
  unsigned r;
  asm("v_cvt_pk_bf16_f32 %0, %1, %2" : "=v"(r) : "v"(lo), "v"(hi));
  return r;
}

// ---------------- k1: Wh = h @ W (fp32), fused src/dst, store Wh as bf16 ----
__global__ __launch_bounds__(512) void k_wh(const float* __restrict__ h,
                                            const float* __restrict__ W,
                                            const float* __restrict__ a1,
                                            const float* __restrict__ a2,
                                            unsigned short* __restrict__ WhB,
                                            float* __restrict__ src,
                                            float* __restrict__ dstv) {
  __shared__ float sA[16][36];    // [k][row]
  __shared__ float sB[16][260];   // [k][col]
  const int tid = threadIdx.x;
  const int wave = tid >> 6;
  const int lane = tid & 63;
  const int bm = blockIdx.x * 32;
  const int arow = tid >> 4;
  const int akk = tid & 15;
  const int bkr = tid >> 5;
  const int bc = (tid & 31) * 8;
  float acc[4][4] = {};
  for (int k0 = 0; k0 < KIN; k0 += 16) {
    float av = h[(size_t)(bm + arow) * KIN + k0 + akk];
    const float4* wp = (const float4*)(W + (size_t)(k0 + bkr) * KOUT + bc);
    float4 w0 = wp[0], w1 = wp[1];
    __syncthreads();
    sA[akk][arow] = av;
    *(float4*)&sB[bkr][bc] = w0;
    *(float4*)&sB[bkr][bc + 4] = w1;
    __syncthreads();
#pragma unroll
    for (int k = 0; k < 16; ++k) {
      float4 a4 = *(const float4*)&sA[k][wave * 4];
      float4 b4 = *(const float4*)&sB[k][lane * 4];
      float aa[4] = {a4.x, a4.y, a4.z, a4.w};
      float bb[4] = {b4.x, b4.y, b4.z, b4.w};
#pragma unroll
      for (int i = 0; i < 4; ++i)
#pragma unroll
        for (int jj = 0; jj < 4; ++jj)
          acc[i][jj] = fmaf(aa[i], bb[jj], acc[i][jj]);
    }
  }
  float4 a1v = *(const float4*)(a1 + lane * 4);
  float4 a2v = *(const float4*)(a2 + lane * 4);
  float sp[4], dp[4];
#pragma unroll
  for (int i = 0; i < 4; ++i) {
    sp[i] = acc[i][0] * a1v.x + acc[i][1] * a1v.y + acc[i][2] * a1v.z + acc[i][3] * a1v.w;
    dp[i] = acc[i][0] * a2v.x + acc[i][1] * a2v.y + acc[i][2] * a2v.z + acc[i][3] * a2v.w;
  }
#pragma unroll
  for (int off = 32; off >= 1; off >>= 1) {
#pragma unroll
    for (int i = 0; i < 4; ++i) {
      sp[i] += __shfl_xor(sp[i], off);
      dp[i] += __shfl_xor(dp[i], off);
    }
  }
  if (lane == 0) {
#pragma unroll
    for (int i = 0; i < 4; ++i) {
      src[bm + wave * 4 + i] = sp[i];
      dstv[bm + wave * 4 + i] = dp[i];
    }
  }
#pragma unroll
  for (int i = 0; i < 4; ++i) {
    ushort4_t pk;
#pragma unroll
    for (int jj = 0; jj < 4; ++jj) pk[jj] = f2bf(acc[i][jj]);
    *(ushort4_t*)(WhB + (size_t)(bm + wave * 4 + i) * KOUT + lane * 4) = pk;
  }
}

// ---- k_trF: WhB[row][col] -> WhF in exact MFMA B-fragment order ----------
__global__ __launch_bounds__(256) void k_trF(const unsigned short* __restrict__ WhB,
                                             unsigned short* __restrict__ WhF) {
  __shared__ unsigned int sX[64][65];
  const int t = threadIdx.x;
  const int r0 = (blockIdx.x & 127) * 64;
  const int c0 = (blockIdx.x >> 7) * 64;
  const int rr = t >> 2;
  const int cq = (t & 3) * 16;
  const ushort8_t* p = (const ushort8_t*)(WhB + (size_t)(r0 + rr) * KOUT + c0 + cq);
  ushort8_t v0 = p[0], v1 = p[1];
#pragma unroll
  for (int i = 0; i < 8; ++i) {
    sX[rr][cq + i] = v0[i];
    sX[rr][cq + 8 + i] = v1[i];
  }
  __syncthreads();
  const int wv = t >> 6;
  const int lane = t & 63;
  const int q = lane >> 4;
  const int fr = lane & 15;
  const int kt = r0 >> 6;
  const int wbase = c0 >> 5;
#pragma unroll
  for (int i = 0; i < 2; ++i) {
    const int g = wv * 2 + i;            // 0..7
    const int wloc = g >> 2;
    const int nc = (g >> 1) & 1;
    const int kh = g & 1;
    const int j0 = kh * 32 + q * 8;
    const int lc = wloc * 32 + nc * 16 + fr;
    ushort8_t o;
#pragma unroll
    for (int e = 0; e < 8; ++e) o[e] = (unsigned short)sX[j0 + e][lc];
    const int w = wbase + wloc;
    const size_t idx = ((((size_t)kt * 8 + w) * 2 + nc) * 2 + kh) * 64 + lane;
    *(ushort8_t*)(WhF + idx * 8) = o;
  }
}

// ---------------- k_dmax ----------------
__global__ __launch_bounds__(256) void k_dmax(const float* __restrict__ dstv,
                                              float* __restrict__ Dp) {
  __shared__ float red[256];
  const int t = threadIdx.x;
  float m = -3e38f;
  for (int i = t; i < NN; i += 256) m = fmaxf(m, dstv[i]);
  red[t] = m;
  __syncthreads();
  for (int s = 128; s >= 1; s >>= 1) {
    if (t < s) red[t] = fmaxf(red[t], red[t + s]);
    __syncthreads();
  }
  if (t == 0) *Dp = red[0];
}

// ---- k_attn: 512 thr (4C+4P), 128x64 consumer tiles, table producers -----
struct Bset { ushort8_t b[4][2]; };  // [nc][kh]

#define MF(a, b, c) __builtin_amdgcn_mfma_f32_16x16x32_bf16(a, b, c, 0, 0, 0)

#define BAR()                                              \
  {                                                        \
    asm volatile("s_waitcnt lgkmcnt(0)" ::: "memory");     \
    __builtin_amdgcn_s_barrier();                          \
    asm volatile("" ::: "memory");                         \
  }

// virtual tile t -> LOCAL k-tile in this quarter (per-block rotation)
#define TI(t) (((t) + ph0) & (NT4 - 1))

// 8 fully-coalesced 1KB fragment loads (64 cols x 64 k)
#define LOADB(BS, ktl)                                                 \
  {                                                                    \
    const unsigned short* p_ = bfw + (size_t)(ktl) * 16384;            \
    BS.b[0][0] = *(const ushort8_t*)(p_);                              \
    BS.b[0][1] = *(const ushort8_t*)(p_ + 512);                        \
    BS.b[1][0] = *(const ushort8_t*)(p_ + 1024);                       \
    BS.b[1][1] = *(const ushort8_t*)(p_ + 1536);                       \
    BS.b[2][0] = *(const ushort8_t*)(p_ + 2048);                       \
    BS.b[2][1] = *(const ushort8_t*)(p_ + 2560);                       \
    BS.b[3][0] = *(const ushort8_t*)(p_ + 3072);                       \
    BS.b[3][1] = *(const ushort8_t*)(p_ + 3584);                       \
  }

// producer: 4 weights via separable-exp tables: w = adj ? max(E1*F1, E2*F2) : 0
#define WGEN4(AJ, ktl, koff, buf)                                      \
  {                                                                    \
    float4 e1 = *(const float4*)&sE1[(ktl) * BK + (koff)];             \
    float4 e2 = *(const float4*)&sE2[(ktl) * BK + (koff)];             \
    float w0 = (AJ.x > 0) ? fmaxf(e1.x * F1, e2.x * F2) : 0.f;         \
    float w1 = (AJ.y > 0) ? fmaxf(e1.y * F1, e2.y * F2) : 0.f;         \
    float w2 = (AJ.z > 0) ? fmaxf(e1.z * F1, e2.z * F2) : 0.f;         \
    float w3 = (AJ.w > 0) ? fmaxf(e1.w * F1, e2.w * F2) : 0.f;         \
    lsum += (w0 + w1) + (w2 + w3);                                     \
    uint2 pk;                                                          \
    pk.x = cvt_pk_bf16(w0, w1);                                        \
    pk.y = cvt_pk_bf16(w2, w3);                                        \
    *(uint2*)(sAb + (buf) * 16384 +                                    \
              ((pr * 128 + (koff) * 2) ^ ((pr & 7) << 4))) = pk;       \
  }

// producer tile body: 32 weights (8 quads), thread covers k [pk32, pk32+32)
#define WGEN32(R, ktl, buf)                                            \
  {                                                                    \
    _Pragma("unroll")                                                  \
    for (int q = 0; q < 8; ++q) { WGEN4(R[q], ktl, pk32 + q * 4, buf); } \
  }

#define LOADADJ32(R, ktl)                                              \
  {                                                                    \
    const int4v* ap = (const int4v*)(adjp + (size_t)(ktl) * BK);       \
    _Pragma("unroll")                                                  \
    for (int q = 0; q < 8; ++q) { R[q] = __builtin_nontemporal_load(ap + q); } \
  }

#define LDA(cur, mr, kk)                                                        \
  __builtin_bit_cast(bf16x8,                                                    \
    *(const ushort8_t*)(sAb + (cur) * 16384 +                                   \
      ((((mr) * 16 + fr) * 128 + (kk) * 64 + fq * 16) ^ ((fr & 7) << 4))))

#define MSTEP(cur, BS)                                                 \
  {                                                                    \
    _Pragma("unroll")                                                  \
    for (int mr = 0; mr < 8; ++mr) {                                   \
      bf16x8 a0 = LDA(cur, mr, 0), a1 = LDA(cur, mr, 1);               \
      _Pragma("unroll")                                                \
      for (int nc = 0; nc < 4; ++nc) {                                 \
        acc[mr][nc] = MF(a0, BS.b[nc][0], acc[mr][nc]);                \
        acc[mr][nc] = MF(a1, BS.b[nc][1], acc[mr][nc]);                \
      }                                                                \
    }                                                                  \
  }

__global__ __launch_bounds__(512, 2) void k_attn(const int* __restrict__ adj,
                                                 const unsigned short* __restrict__ WhF,
                                                 const float* __restrict__ src,
                                                 const float* __restrict__ dstv,
                                                 const float* __restrict__ Dp,
                                                 float* __restrict__ Pbuf,
                                                 float* __restrict__ Lsum) {
  __shared__ unsigned short sA[2][ROWS][BK];  // 32 KB dbuf, XOR-swizzled rows
  __shared__ float sE1[KQ];                   // 8 KB: exp(d_j)
  __shared__ float sE2[KQ];                   // 8 KB: exp(0.2 d_j)
  char* sAb = (char*)&sA[0][0][0];
  const int tid = threadIdx.x;
  const int lane = tid & 63;
  const int wave = tid >> 6;      // 0..3 consumers, 4..7 producers
  const int qtr = blockIdx.x & 3;
  const int rg = blockIdx.x >> 2;
  const int r0 = rg * ROWS;
  const int ph0 = rg & (NT4 - 1);
  const int kbase = qtr * KQ;
  const float D = *Dp;

  // build exp tables for this quarter's dstv slice (512 thr x 4)
  {
    float4 d4 = *(const float4*)(dstv + kbase + tid * 4);
    float4 t1, t2;
    t1.x = __expf(d4.x); t1.y = __expf(d4.y); t1.z = __expf(d4.z); t1.w = __expf(d4.w);
    t2.x = __expf(ALPHA * d4.x); t2.y = __expf(ALPHA * d4.y);
    t2.z = __expf(ALPHA * d4.z); t2.w = __expf(ALPHA * d4.w);
    *(float4*)&sE1[tid * 4] = t1;
    *(float4*)&sE2[tid * 4] = t2;
  }
  __syncthreads();

  // ---------- producer state (waves 4..7): 2 threads per row ----------
  const int ptid = tid - 256;               // 0..255
  const int pr = ptid >> 1;                 // 0..127
  const int pk32 = (ptid & 1) * 32;         // k-offset within tile
  const float s_r = src[r0 + pr];
  const float c_r = lrelu(s_r + D);
  const float F1 = __expf(s_r - c_r);
  const float F2 = __expf(ALPHA * s_r - c_r);
  const int* adjp = adj + (size_t)(r0 + pr) * NN + kbase + pk32;
  float lsum = 0.f;

  // ---------- consumer state (waves 0..3): wave tile 128x64 ----------
  const int fr = lane & 15;
  const int fq = lane >> 4;
  const unsigned short* bfw =
      WhF + ((size_t)(qtr * NT4) * 8 + wave * 2) * 2048 + lane * 8;
  f32x4 acc[8][4];
#pragma unroll
  for (int mr = 0; mr < 8; ++mr)
#pragma unroll
    for (int nc = 0; nc < 4; ++nc) acc[mr][nc] = (f32x4){0.f, 0.f, 0.f, 0.f};
  Bset B0, B1;
  int4v aA[8], aB[8];   // adj slack slots (even/odd tiles)

  // ---------- prologue ----------
  if (wave >= 4) {
    int4v d[8];
    {
      const int4v* ap = (const int4v*)(adjp + (size_t)TI(0) * BK);
#pragma unroll
      for (int q = 0; q < 8; ++q) d[q] = ap[q];
    }
    WGEN32(d, TI(0), 0);
    LOADADJ32(aB, TI(1));
    LOADADJ32(aA, TI(2));
  } else {
    LOADB(B0, TI(0));
    LOADB(B1, TI(1));
  }
  BAR();

  // ---------- main loop: NT4 tiles, 1 barrier per tile ----------
  if (wave < 4) {
#pragma unroll 1
    for (int p = 0; p < NT4; p += 2) {
      { MSTEP(0, B0); LOADB(B0, TI(p + 2 < NT4 ? p + 2 : NT4 - 1)); BAR(); }
      { MSTEP(1, B1); LOADB(B1, TI(p + 3 < NT4 ? p + 3 : NT4 - 1)); BAR(); }
    }
    // store raw partial accumulators
#pragma unroll
    for (int mr = 0; mr < 8; ++mr) {
#pragma unroll
      for (int r = 0; r < 4; ++r) {
        const int row = mr * 16 + fq * 4 + r;
#pragma unroll
        for (int nc = 0; nc < 4; ++nc) {
          const int col = wave * 64 + nc * 16 + fr;
          Pbuf[(size_t)(qtr * NN + r0 + row) * KOUT + col] = acc[mr][nc][r];
        }
      }
    }
  } else {
#pragma unroll 1
    for (int p = 0; p < NT4; p += 2) {
      // phase p: WGEN tile p+1 (slot aB), reload aB <- tile p+3
      {
        WGEN32(aB, TI(p + 1), 1);
        LOADADJ32(aB, TI(p + 3 < NT4 ? p + 3 : NT4 - 1));
        BAR();
      }
      // phase p+1: WGEN tile p+2 (slot aA), reload aA <- tile p+4
      {
        if (p + 2 < NT4) { WGEN32(aA, TI(p + 2), 0); }
        LOADADJ32(aA, TI(p + 4 < NT4 ? p + 4 : NT4 - 1));
        BAR();
      }
    }
    // row-sum reduce across the 2 threads sharing a row
    lsum += __shfl_xor(lsum, 1, 2);
    if ((ptid & 1) == 0) Lsum[qtr * NN + r0 + pr] = lsum;
  }
}

// ---------------- k_comb: out = elu(sum(P)/sum(L)) -----------------------
__global__ __launch_bounds__(256) void k_comb(const float* __restrict__ Pbuf,
                                              const float* __restrict__ Lsum,
                                              float* __restrict__ out) {
  const int t = threadIdx.x;
  const int row = blockIdx.x * 4 + (t >> 6);
  const int col = (t & 63) * 4;
  const float l = Lsum[row] + Lsum[NN + row] + Lsum[2 * NN + row] + Lsum[3 * NN + row];
  float4 p0 = *(const float4*)(Pbuf + (size_t)row * KOUT + col);
  float4 p1 = *(const float4*)(Pbuf + (size_t)(NN + row) * KOUT + col);
  float4 p2 = *(const float4*)(Pbuf + (size_t)(2 * NN + row) * KOUT + col);
  float4 p3 = *(const float4*)(Pbuf + (size_t)(3 * NN + row) * KOUT + col);
  float4 v;
  v.x = (p0.x + p1.x + p2.x + p3.x) / l;
  v.y = (p0.y + p1.y + p2.y + p3.y) / l;
  v.z = (p0.z + p1.z + p2.z + p3.z) / l;
  v.w = (p0.w + p1.w + p2.w + p3.w) / l;
  v.x = v.x > 0.f ? v.x : __expf(v.x) - 1.f;
  v.y = v.y > 0.f ? v.y : __expf(v.y) - 1.f;
  v.z = v.z > 0.f ? v.z : __expf(v.z) - 1.f;
  v.w = v.w > 0.f ? v.w : __expf(v.w) - 1.f;
  *(float4*)(out + (size_t)row * KOUT + col) = v;
}

extern "C" void kernel_launch(void* const* d_in, const int* in_sizes, int n_in,
                              void* d_out, int out_size, void* d_ws, size_t ws_size,
                              hipStream_t stream) {
  const float* h = (const float*)d_in[0];
  const int* adj = (const int*)d_in[1];
  const float* W = (const float*)d_in[2];
  const float* a1 = (const float*)d_in[3];
  const float* a2 = (const float*)d_in[4];
  float* out = (float*)d_out;

  unsigned short* WhB = (unsigned short*)d_ws;            // 4 MB
  unsigned short* WhF = WhB + (size_t)NN * KOUT;          // 4 MB (fragment order)
  float* src = (float*)(WhF + (size_t)NN * KOUT);         // 32 KB
  float* dstv = src + NN;                                 // 32 KB
  float* Dp = dstv + NN;                                  // pad
  float* Pbuf = Dp + 16;                                  // 32 MB partials
  float* Lsum = Pbuf + (size_t)4 * NN * KOUT;             // 128 KB

  hipLaunchKernelGGL(k_wh, dim3(NN / 32), dim3(512), 0, stream, h, W, a1, a2, WhB, src, dstv);
  hipLaunchKernelGGL(k_trF, dim3(512), dim3(256), 0, stream, WhB, WhF);
  hipLaunchKernelGGL(k_dmax, dim3(1), dim3(256), 0, stream, dstv, Dp);
  hipLaunchKernelGGL(k_attn, dim3(256), dim3(512), 0, stream, adj, WhF, src, dstv, Dp, Pbuf, Lsum);
  hipLaunchKernelGGL(k_comb, dim3(NN / 4), dim3(256), 0, stream, Pbuf, Lsum, out);
}

// Round 16
// 138.744 us; speedup vs baseline: 1.3963x; 1.3963x over previous
//
#include <hip/hip_runtime.h>
#include <hip/hip_bf16.h>

#define NN 8192
#define KIN 512
#define KOUT 256
#define ALPHA 0.2f
#define BK 64
#define ROWS 128        // rows per block (k_attn)
#define KQ (NN / 4)     // k-range per quarter
#define NT4 (KQ / BK)   // 32 k-tiles per quarter

typedef __bf16 bf16x8 __attribute__((ext_vector_type(8)));
typedef float f32x4 __attribute__((ext_vector_type(4)));
typedef unsigned short ushort8_t __attribute__((ext_vector_type(8)));
typedef int int4v __attribute__((ext_vector_type(4)));

__device__ __forceinline__ float lrelu(float x) { return x > 0.f ? x : ALPHA * x; }

__device__ __forceinline__ unsigned short f2bf(float f) {
  union { float f; unsigned u; } v; v.f = f;
  unsigned r = v.u + 0x7fffu + ((v.u >> 16) & 1u);  // RNE to bf16
  return (unsigned short)(r >> 16);
}

// pack two f32 -> one u32 of 2x bf16 (RNE) via HW instruction
__device__ __forceinline__ unsigned cvt_pk_bf16(float lo, float hi) {
  unsigned r;
  asm("v_cvt_pk_bf16_f32 %0, %1, %2" : "=v"(r) : "v"(lo), "v"(hi));
  return r;
}

// monotone float->uint key for atomicMax
__device__ __forceinline__ unsigned fkey(float x) {
  unsigned b = __float_as_uint(x);
  return (b & 0x80000000u) ? ~b : (b | 0x80000000u);
}
__device__ __forceinline__ float funkey(unsigned k) {
  unsigned b = (k & 0x80000000u) ? (k ^ 0x80000000u) : ~k;
  return __uint_as_float(b);
}

#define MF(a, b, c) __builtin_amdgcn_mfma_f32_16x16x32_bf16(a, b, c, 0, 0, 0)

// ---------------- k_wa: Wa1 = W@a1, Wa2 = W@a2; init Dp key ----------------
__global__ __launch_bounds__(256) void k_wa(const float* __restrict__ W,
                                            const float* __restrict__ a1,
                                            const float* __restrict__ a2,
                                            float* __restrict__ Wa1,
                                            float* __restrict__ Wa2,
                                            unsigned* __restrict__ Dup) {
  const int k = blockIdx.x * 256 + threadIdx.x;  // 0..511
  float s1 = 0.f, s2 = 0.f;
  const float* wr = W + (size_t)k * KOUT;
  for (int c = 0; c < KOUT; c += 4) {
    float4 w4 = *(const float4*)(wr + c);
    float4 b1 = *(const float4*)(a1 + c);
    float4 b2 = *(const float4*)(a2 + c);
    s1 += w4.x * b1.x + w4.y * b1.y + w4.z * b1.z + w4.w * b1.w;
    s2 += w4.x * b2.x + w4.y * b2.y + w4.z * b2.z + w4.w * b2.w;
  }
  Wa1[k] = s1;
  Wa2[k] = s2;
  if (k == 0) *Dup = 0u;  // key(x) > 0 for any real float
}

// ---------------- k_prep: W (fp32) -> Wb bf16 in MFMA B-fragment order -----
// frag (kt, cg): lane l holds W[kt*32 + (l>>4)*8 + e][cg*16 + (l&15)]
__global__ __launch_bounds__(64) void k_prep(const float* __restrict__ W,
                                             unsigned short* __restrict__ Wb) {
  const int b = blockIdx.x;       // 0..255 = kt*16 + cg
  const int kt = b >> 4, cg = b & 15;
  const int l = threadIdx.x;
  const int krow = kt * 32 + (l >> 4) * 8;
  const int col = cg * 16 + (l & 15);
  ushort8_t o;
#pragma unroll
  for (int e = 0; e < 8; ++e) o[e] = f2bf(W[(size_t)(krow + e) * KOUT + col]);
  *(ushort8_t*)(Wb + ((size_t)b * 64 + l) * 8) = o;
}

// ---------------- k_wh2: Wh = h @ W via MFMA; src/dst fp32; Dp atomicMax ---
// grid 128 blocks x 512 thr (8 waves); M-tile 64, wave out 64x32
__global__ __launch_bounds__(512) void k_wh2(const float* __restrict__ h,
                                             const unsigned short* __restrict__ Wb,
                                             const float* __restrict__ Wa1,
                                             const float* __restrict__ Wa2,
                                             unsigned short* __restrict__ WhB,
                                             float* __restrict__ src,
                                             float* __restrict__ dstv,
                                             unsigned* __restrict__ Dup) {
  __shared__ unsigned short sH[64][64];        // 8 KB, XOR-swizzled rows
  __shared__ unsigned short sBounce[64][128];  // 16 KB epilogue bounce
  __shared__ float sW1[KIN], sW2[KIN];         // 4 KB
  char* sHb = (char*)&sH[0][0];
  const int tid = threadIdx.x;
  const int lane = tid & 63;
  const int wv = tid >> 6;       // 0..7
  const int r0 = blockIdx.x * 64;
  const int fr = lane & 15, fq = lane >> 4;

  sW1[tid] = Wa1[tid];
  sW2[tid] = Wa2[tid];

  // staging role: row srow (0..63), k-chunk skc (8 floats)
  const int srow = tid >> 3;
  const int skc = (tid & 7) * 8;
  const float* hp = h + (size_t)(r0 + srow) * KIN + skc;
  const int wby = ((srow * 128 + skc * 2) ^ ((srow & 7) << 4));
  float sp = 0.f, dp = 0.f;

  f32x4 acc[4][2];
#pragma unroll
  for (int mr = 0; mr < 4; ++mr) {
    acc[mr][0] = (f32x4){0.f, 0.f, 0.f, 0.f};
    acc[mr][1] = (f32x4){0.f, 0.f, 0.f, 0.f};
  }
  ushort8_t Bs[2][2];  // [n][kk]

  float hv[8];
  {
    float4 a = *(const float4*)hp;
    float4 b = *(const float4*)(hp + 4);
    hv[0] = a.x; hv[1] = a.y; hv[2] = a.z; hv[3] = a.w;
    hv[4] = b.x; hv[5] = b.y; hv[6] = b.z; hv[7] = b.w;
  }

#pragma unroll 1
  for (int it = 0; it < 8; ++it) {
    __syncthreads();  // sH consumers of previous iter done (also covers sW stage)
    // src/dst partials + bf16 pack + LDS write
    const int kb = it * 64 + skc;
#pragma unroll
    for (int j = 0; j < 8; ++j) {
      sp = fmaf(hv[j], sW1[kb + j], sp);
      dp = fmaf(hv[j], sW2[kb + j], dp);
    }
    uint4 pk;
    pk.x = cvt_pk_bf16(hv[0], hv[1]);
    pk.y = cvt_pk_bf16(hv[2], hv[3]);
    pk.z = cvt_pk_bf16(hv[4], hv[5]);
    pk.w = cvt_pk_bf16(hv[6], hv[7]);
    *(uint4*)(sHb + wby) = pk;
    // issue next h loads early
    float hn[8];
    if (it < 7) {
      float4 a = *(const float4*)(hp + (it + 1) * 64);
      float4 b = *(const float4*)(hp + (it + 1) * 64 + 4);
      hn[0] = a.x; hn[1] = a.y; hn[2] = a.z; hn[3] = a.w;
      hn[4] = b.x; hn[5] = b.y; hn[6] = b.z; hn[7] = b.w;
    }
    __syncthreads();  // sH tile ready
    // B frags: (kt = it*2 + kk, cg = wv*2 + n)
#pragma unroll
    for (int n = 0; n < 2; ++n)
#pragma unroll
      for (int kk = 0; kk < 2; ++kk)
        Bs[n][kk] = *(const ushort8_t*)(Wb +
            (((size_t)(it * 2 + kk) * 16 + wv * 2 + n) * 64 + lane) * 8);
    // MFMA
#pragma unroll
    for (int mr = 0; mr < 4; ++mr) {
      bf16x8 a0 = __builtin_bit_cast(bf16x8, *(const ushort8_t*)(sHb +
          (((mr * 16 + fr) * 128 + 0 * 64 + fq * 16) ^ ((fr & 7) << 4))));
      bf16x8 a1 = __builtin_bit_cast(bf16x8, *(const ushort8_t*)(sHb +
          (((mr * 16 + fr) * 128 + 1 * 64 + fq * 16) ^ ((fr & 7) << 4))));
      acc[mr][0] = MF(a0, Bs[0][0], acc[mr][0]);
      acc[mr][0] = MF(a1, Bs[0][1], acc[mr][0]);
      acc[mr][1] = MF(a0, Bs[1][0], acc[mr][1]);
      acc[mr][1] = MF(a1, Bs[1][1], acc[mr][1]);
    }
#pragma unroll
    for (int j = 0; j < 8; ++j) hv[j] = hn[j];
  }

  // src/dst reduce across the 8 threads of a row (adjacent lanes)
  sp += __shfl_xor(sp, 1, 8);
  sp += __shfl_xor(sp, 2, 8);
  sp += __shfl_xor(sp, 4, 8);
  dp += __shfl_xor(dp, 1, 8);
  dp += __shfl_xor(dp, 2, 8);
  dp += __shfl_xor(dp, 4, 8);
  if ((tid & 7) == 0) {
    src[r0 + srow] = sp;
    dstv[r0 + srow] = dp;
    atomicMax(Dup, fkey(dp));
  }

  // epilogue: bounce acc -> row-major bf16 WhB (two passes of 4 waves)
#pragma unroll 1
  for (int pass = 0; pass < 2; ++pass) {
    __syncthreads();
    if ((wv >> 2) == pass) {
      const int fbase = (wv & 3) * 32;
#pragma unroll
      for (int mr = 0; mr < 4; ++mr)
#pragma unroll
        for (int n = 0; n < 2; ++n)
#pragma unroll
          for (int r = 0; r < 4; ++r)
            sBounce[mr * 16 + fq * 4 + r][fbase + n * 16 + fr] =
                f2bf(acc[mr][n][r]);
    }
    __syncthreads();
    // copy 16KB: thread t -> row t>>3, 16 feats
    const int crow = tid >> 3;
    const int cfo = (tid & 7) * 16;
    *(ushort8_t*)(WhB + (size_t)(r0 + crow) * KOUT + pass * 128 + cfo) =
        *(const ushort8_t*)&sBounce[crow][cfo];
    *(ushort8_t*)(WhB + (size_t)(r0 + crow) * KOUT + pass * 128 + cfo + 8) =
        *(const ushort8_t*)&sBounce[crow][cfo + 8];
  }
}

// ---- k_trF: WhB[row][col] -> WhF in exact MFMA B-fragment order ----------
__global__ __launch_bounds__(256) void k_trF(const unsigned short* __restrict__ WhB,
                                             unsigned short* __restrict__ WhF) {
  __shared__ unsigned int sX[64][65];
  const int t = threadIdx.x;
  const int r0 = (blockIdx.x & 127) * 64;
  const int c0 = (blockIdx.x >> 7) * 64;
  const int rr = t >> 2;
  const int cq = (t & 3) * 16;
  const ushort8_t* p = (const ushort8_t*)(WhB + (size_t)(r0 + rr) * KOUT + c0 + cq);
  ushort8_t v0 = p[0], v1 = p[1];
#pragma unroll
  for (int i = 0; i < 8; ++i) {
    sX[rr][cq + i] = v0[i];
    sX[rr][cq + 8 + i] = v1[i];
  }
  __syncthreads();
  const int wv = t >> 6;
  const int lane = t & 63;
  const int q = lane >> 4;
  const int fr = lane & 15;
  const int kt = r0 >> 6;
  const int wbase = c0 >> 5;
#pragma unroll
  for (int i = 0; i < 2; ++i) {
    const int g = wv * 2 + i;            // 0..7
    const int wloc = g >> 2;
    const int nc = (g >> 1) & 1;
    const int kh = g & 1;
    const int j0 = kh * 32 + q * 8;
    const int lc = wloc * 32 + nc * 16 + fr;
    ushort8_t o;
#pragma unroll
    for (int e = 0; e < 8; ++e) o[e] = (unsigned short)sX[j0 + e][lc];
    const int w = wbase + wloc;
    const size_t idx = ((((size_t)kt * 8 + w) * 2 + nc) * 2 + kh) * 64 + lane;
    *(ushort8_t*)(WhF + idx * 8) = o;
  }
}

// ---- k_attn: R14 optimum (2-slot B, 128x32 consumer tiles, lean prods) ---
struct Bset { ushort8_t b[2][2]; };  // [nc][kh]

#define BAR()                                              \
  {                                                        \
    asm volatile("s_waitcnt lgkmcnt(0)" ::: "memory");     \
    __builtin_amdgcn_s_barrier();                          \
    asm volatile("" ::: "memory");                         \
  }

#define TI(t) (((t) + ph0) & (NT4 - 1))

#define LOADB(BS, ktl)                                                 \
  {                                                                    \
    const unsigned short* p_ = bfw + (size_t)(ktl) * 16384;            \
    BS.b[0][0] = *(const ushort8_t*)(p_);                              \
    BS.b[0][1] = *(const ushort8_t*)(p_ + 512);                        \
    BS.b[1][0] = *(const ushort8_t*)(p_ + 1024);                       \
    BS.b[1][1] = *(const ushort8_t*)(p_ + 1536);                       \
  }

#define WGEN4(AJ, ktl, koff, buf)                                      \
  {                                                                    \
    float4 dv = *(const float4*)&sD[(ktl) * BK + (koff)];              \
    float x0 = s_r + dv.x, x1 = s_r + dv.y;                            \
    float x2 = s_r + dv.z, x3 = s_r + dv.w;                            \
    float w0 = (AJ.x > 0) ? __expf(fmaxf(x0, ALPHA * x0) - c_r) : 0.f; \
    float w1 = (AJ.y > 0) ? __expf(fmaxf(x1, ALPHA * x1) - c_r) : 0.f; \
    float w2 = (AJ.z > 0) ? __expf(fmaxf(x2, ALPHA * x2) - c_r) : 0.f; \
    float w3 = (AJ.w > 0) ? __expf(fmaxf(x3, ALPHA * x3) - c_r) : 0.f; \
    lsum += (w0 + w1) + (w2 + w3);                                     \
    uint2 pk;                                                          \
    pk.x = cvt_pk_bf16(w0, w1);                                        \
    pk.y = cvt_pk_bf16(w2, w3);                                        \
    *(uint2*)(sAb + (buf) * 16384 +                                    \
              ((pr * 128 + (koff) * 2) ^ ((pr & 7) << 4))) = pk;       \
  }

#define WGEN16(A0, A1, A2, A3, ktl, buf)                               \
  {                                                                    \
    WGEN4(A0, ktl, pk16 + 0, buf);                                     \
    WGEN4(A1, ktl, pk16 + 4, buf);                                     \
    WGEN4(A2, ktl, pk16 + 8, buf);                                     \
    WGEN4(A3, ktl, pk16 + 12, buf);                                    \
  }

#define LOADADJ16(A0, A1, A2, A3, ktl)                                 \
  {                                                                    \
    const int4v* ap = (const int4v*)(adjp + (size_t)(ktl) * BK);       \
    A0 = __builtin_nontemporal_load(ap);                               \
    A1 = __builtin_nontemporal_load(ap + 1);                           \
    A2 = __builtin_nontemporal_load(ap + 2);                           \
    A3 = __builtin_nontemporal_load(ap + 3);                           \
  }

#define LDA(cur, mr, kk)                                                        \
  __builtin_bit_cast(bf16x8,                                                    \
    *(const ushort8_t*)(sAb + (cur) * 16384 +                                   \
      ((((mr) * 16 + fr) * 128 + (kk) * 64 + fq * 16) ^ ((fr & 7) << 4))))

#define MSTEP(cur, BS)                                                 \
  {                                                                    \
    _Pragma("unroll")                                                  \
    for (int mr = 0; mr < 8; ++mr) {                                   \
      bf16x8 a0 = LDA(cur, mr, 0), a1 = LDA(cur, mr, 1);               \
      acc[mr][0] = MF(a0, BS.b[0][0], acc[mr][0]);                     \
      acc[mr][0] = MF(a1, BS.b[0][1], acc[mr][0]);                     \
      acc[mr][1] = MF(a0, BS.b[1][0], acc[mr][1]);                     \
      acc[mr][1] = MF(a1, BS.b[1][1], acc[mr][1]);                     \
    }                                                                  \
  }

__global__ __launch_bounds__(1024) void k_attn(const int* __restrict__ adj,
                                               const unsigned short* __restrict__ WhF,
                                               const float* __restrict__ src,
                                               const float* __restrict__ dstv,
                                               const unsigned* __restrict__ Dup,
                                               float* __restrict__ Pbuf,
                                               float* __restrict__ Lsum) {
  __shared__ unsigned short sA[2][ROWS][BK];  // 32 KB dbuf, XOR-swizzled rows
  __shared__ float sD[KQ];                    // 8 KB: this quarter's dstv
  char* sAb = (char*)&sA[0][0][0];
  const int tid = threadIdx.x;
  const int lane = tid & 63;
  const int wave = tid >> 6;      // 0..7 consumers, 8..15 producers
  const int qtr = blockIdx.x & 3;
  const int rg = blockIdx.x >> 2;
  const int r0 = rg * ROWS;
  const int ph0 = rg & (NT4 - 1);
  const int kbase = qtr * KQ;
  const float D = funkey(*Dup);

  *(float2*)&sD[tid * 2] = *(const float2*)(dstv + kbase + tid * 2);
  __syncthreads();

  // ---------- producer state (waves 8..15): 4 threads per row ----------
  const int ptid = tid - 512;
  const int pr = ptid >> 2;
  const int pk16 = (ptid & 3) * 16;
  const float s_r = src[r0 + pr];
  const float c_r = lrelu(s_r + D);
  const int* adjp = adj + (size_t)(r0 + pr) * NN + kbase + pk16;
  float lsum = 0.f;

  // ---------- consumer state (waves 0..7): wave tile 128x32 ----------
  const int fr = lane & 15;
  const int fq = lane >> 4;
  const unsigned short* bfw =
      WhF + ((size_t)(qtr * NT4) * 8 + wave) * 2048 + lane * 8;
  f32x4 acc[8][2];
#pragma unroll
  for (int mr = 0; mr < 8; ++mr) {
    acc[mr][0] = (f32x4){0.f, 0.f, 0.f, 0.f};
    acc[mr][1] = (f32x4){0.f, 0.f, 0.f, 0.f};
  }
  Bset B0, B1;
  int4v aA0, aA1, aA2, aA3;
  int4v aB0, aB1, aB2, aB3;

  // ---------- prologue ----------
  if (wave >= 8) {
    int4v d0, d1, d2, d3;
    {
      const int4v* ap = (const int4v*)(adjp + (size_t)TI(0) * BK);
      d0 = ap[0]; d1 = ap[1]; d2 = ap[2]; d3 = ap[3];
    }
    WGEN16(d0, d1, d2, d3, TI(0), 0);
    LOADADJ16(aB0, aB1, aB2, aB3, TI(1));
    LOADADJ16(aA0, aA1, aA2, aA3, TI(2));
  } else {
    LOADB(B0, TI(0));
    LOADB(B1, TI(1));
  }
  BAR();

  // ---------- main loop ----------
  if (wave < 8) {
#pragma unroll 1
    for (int p = 0; p < NT4; p += 2) {
      { MSTEP(0, B0); LOADB(B0, TI(p + 2)); BAR(); }
      { MSTEP(1, B1); LOADB(B1, TI(p + 3)); BAR(); }
    }
#pragma unroll
    for (int mr = 0; mr < 8; ++mr) {
#pragma unroll
      for (int r = 0; r < 4; ++r) {
        const int row = mr * 16 + fq * 4 + r;
#pragma unroll
        for (int nc = 0; nc < 2; ++nc) {
          const int col = wave * 32 + nc * 16 + fr;
          Pbuf[(size_t)(qtr * NN + r0 + row) * KOUT + col] = acc[mr][nc][r];
        }
      }
    }
  } else {
#pragma unroll 1
    for (int p = 0; p < NT4; p += 2) {
      {
        WGEN16(aB0, aB1, aB2, aB3, TI(p + 1), 1);
        LOADADJ16(aB0, aB1, aB2, aB3, TI(p + 3));
        BAR();
      }
      {
        if (p + 2 < NT4) { WGEN16(aA0, aA1, aA2, aA3, TI(p + 2), 0); }
        LOADADJ16(aA0, aA1, aA2, aA3, TI(p + 4));
        BAR();
      }
    }
    lsum += __shfl_xor(lsum, 1, 4);
    lsum += __shfl_xor(lsum, 2, 4);
    if ((ptid & 3) == 0) Lsum[qtr * NN + r0 + pr] = lsum;
  }
}

// ---------------- k_comb: out = elu(sum(P)/sum(L)) -----------------------
__global__ __launch_bounds__(256) void k_comb(const float* __restrict__ Pbuf,
                                              const float* __restrict__ Lsum,
                                              float* __restrict__ out) {
  const int t = threadIdx.x;
  const int row = blockIdx.x * 4 + (t >> 6);
  const int col = (t & 63) * 4;
  const float l = Lsum[row] + Lsum[NN + row] + Lsum[2 * NN + row] + Lsum[3 * NN + row];
  float4 p0 = *(const float4*)(Pbuf + (size_t)row * KOUT + col);
  float4 p1 = *(const float4*)(Pbuf + (size_t)(NN + row) * KOUT + col);
  float4 p2 = *(const float4*)(Pbuf + (size_t)(2 * NN + row) * KOUT + col);
  float4 p3 = *(const float4*)(Pbuf + (size_t)(3 * NN + row) * KOUT + col);
  float4 v;
  v.x = (p0.x + p1.x + p2.x + p3.x) / l;
  v.y = (p0.y + p1.y + p2.y + p3.y) / l;
  v.z = (p0.z + p1.z + p2.z + p3.z) / l;
  v.w = (p0.w + p1.w + p2.w + p3.w) / l;
  v.x = v.x > 0.f ? v.x : __expf(v.x) - 1.f;
  v.y = v.y > 0.f ? v.y : __expf(v.y) - 1.f;
  v.z = v.z > 0.f ? v.z : __expf(v.z) - 1.f;
  v.w = v.w > 0.f ? v.w : __expf(v.w) - 1.f;
  *(float4*)(out + (size_t)row * KOUT + col) = v;
}

extern "C" void kernel_launch(void* const* d_in, const int* in_sizes, int n_in,
                              void* d_out, int out_size, void* d_ws, size_t ws_size,
                              hipStream_t stream) {
  const float* h = (const float*)d_in[0];
  const int* adj = (const int*)d_in[1];
  const float* W = (const float*)d_in[2];
  const float* a1 = (const float*)d_in[3];
  const float* a2 = (const float*)d_in[4];
  float* out = (float*)d_out;

  unsigned short* WhB = (unsigned short*)d_ws;            // 4 MB
  unsigned short* WhF = WhB + (size_t)NN * KOUT;          // 4 MB (fragment order)
  float* src = (float*)(WhF + (size_t)NN * KOUT);         // 32 KB
  float* dstv = src + NN;                                 // 32 KB
  unsigned* Dup = (unsigned*)(dstv + NN);                 // pad 16
  float* Pbuf = (float*)(Dup + 16);                       // 32 MB partials
  float* Lsum = Pbuf + (size_t)4 * NN * KOUT;             // 128 KB
  unsigned short* Wb = (unsigned short*)(Lsum + 4 * NN);  // 256 KB frag W
  float* Wa1 = (float*)(Wb + (size_t)KIN * KOUT);         // 2 KB
  float* Wa2 = Wa1 + KIN;                                 // 2 KB

  hipLaunchKernelGGL(k_wa, dim3(2), dim3(256), 0, stream, W, a1, a2, Wa1, Wa2, Dup);
  hipLaunchKernelGGL(k_prep, dim3(256), dim3(64), 0, stream, W, Wb);
  hipLaunchKernelGGL(k_wh2, dim3(NN / 64), dim3(512), 0, stream,
                     h, Wb, Wa1, Wa2, WhB, src, dstv, Dup);
  hipLaunchKernelGGL(k_trF, dim3(512), dim3(256), 0, stream, WhB, WhF);
  hipLaunchKernelGGL(k_attn, dim3(256), dim3(1024), 0, stream,
                     adj, WhF, src, dstv, Dup, Pbuf, Lsum);
  hipLaunchKernelGGL(k_comb, dim3(NN / 4), dim3(256), 0, stream, Pbuf, Lsum, out);
}

// Round 17
// 135.856 us; speedup vs baseline: 1.4260x; 1.0213x over previous
//
#include <hip/hip_runtime.h>
#include <hip/hip_bf16.h>

#define NN 8192
#define KIN 512
#define KOUT 256
#define ALPHA 0.2f
#define BK 64
#define ROWS 128        // rows per block (k_attn)
#define KQ (NN / 4)     // k-range per quarter
#define NT4 (KQ / BK)   // 32 k-tiles per quarter

typedef __bf16 bf16x8 __attribute__((ext_vector_type(8)));
typedef float f32x4 __attribute__((ext_vector_type(4)));
typedef unsigned short ushort8_t __attribute__((ext_vector_type(8)));
typedef int int4v __attribute__((ext_vector_type(4)));

__device__ __forceinline__ float lrelu(float x) { return x > 0.f ? x : ALPHA * x; }

__device__ __forceinline__ unsigned short f2bf(float f) {
  union { float f; unsigned u; } v; v.f = f;
  unsigned r = v.u + 0x7fffu + ((v.u >> 16) & 1u);  // RNE to bf16
  return (unsigned short)(r >> 16);
}

// pack two f32 -> one u32 of 2x bf16 (RNE) via HW instruction
__device__ __forceinline__ unsigned cvt_pk_bf16(float lo, float hi) {
  unsigned r;
  asm("v_cvt_pk_bf16_f32 %0, %1, %2" : "=v"(r) : "v"(lo), "v"(hi));
  return r;
}

// monotone float->uint key for atomicMax
__device__ __forceinline__ unsigned fkey(float x) {
  unsigned b = __float_as_uint(x);
  return (b & 0x80000000u) ? ~b : (b | 0x80000000u);
}
__device__ __forceinline__ float funkey(unsigned k) {
  unsigned b = (k & 0x80000000u) ? (k ^ 0x80000000u) : ~k;
  return __uint_as_float(b);
}

#define MF(a, b, c) __builtin_amdgcn_mfma_f32_16x16x32_bf16(a, b, c, 0, 0, 0)

// ---------------- k_wa: Wa1 = W@a1, Wa2 = W@a2; init Dp key ----------------
__global__ __launch_bounds__(256) void k_wa(const float* __restrict__ W,
                                            const float* __restrict__ a1,
                                            const float* __restrict__ a2,
                                            float* __restrict__ Wa1,
                                            float* __restrict__ Wa2,
                                            unsigned* __restrict__ Dup) {
  const int k = blockIdx.x * 256 + threadIdx.x;  // 0..511
  float s1 = 0.f, s2 = 0.f;
  const float* wr = W + (size_t)k * KOUT;
  for (int c = 0; c < KOUT; c += 4) {
    float4 w4 = *(const float4*)(wr + c);
    float4 b1 = *(const float4*)(a1 + c);
    float4 b2 = *(const float4*)(a2 + c);
    s1 += w4.x * b1.x + w4.y * b1.y + w4.z * b1.z + w4.w * b1.w;
    s2 += w4.x * b2.x + w4.y * b2.y + w4.z * b2.z + w4.w * b2.w;
  }
  Wa1[k] = s1;
  Wa2[k] = s2;
  if (k == 0) *Dup = 0u;  // key(x) > 0 for any real float
}

// ---------------- k_prep: W (fp32) -> Wb bf16 in MFMA B-fragment order -----
// frag (kt, cg): lane l holds W[kt*32 + (l>>4)*8 + e][cg*16 + (l&15)]
__global__ __launch_bounds__(64) void k_prep(const float* __restrict__ W,
                                             unsigned short* __restrict__ Wb) {
  const int b = blockIdx.x;       // 0..255 = kt*16 + cg
  const int kt = b >> 4, cg = b & 15;
  const int l = threadIdx.x;
  const int krow = kt * 32 + (l >> 4) * 8;
  const int col = cg * 16 + (l & 15);
  ushort8_t o;
#pragma unroll
  for (int e = 0; e < 8; ++e) o[e] = f2bf(W[(size_t)(krow + e) * KOUT + col]);
  *(ushort8_t*)(Wb + ((size_t)b * 64 + l) * 8) = o;
}

// -------- k_wh2: Wh = h @ W via MFMA; writes WhF fragment-order direct -----
// grid 128 blocks x 512 thr (8 waves); M-tile 64 (= one kt), wave out 64x32
__global__ __launch_bounds__(512) void k_wh2(const float* __restrict__ h,
                                             const unsigned short* __restrict__ Wb,
                                             const float* __restrict__ Wa1,
                                             const float* __restrict__ Wa2,
                                             unsigned short* __restrict__ WhF,
                                             float* __restrict__ src,
                                             float* __restrict__ dstv,
                                             unsigned* __restrict__ Dup) {
  __shared__ unsigned short sH[64][64];        // 8 KB, XOR-swizzled rows
  __shared__ unsigned short sBounce[64][132];  // 16.5 KB epilogue bounce (padded)
  __shared__ float sW1[KIN], sW2[KIN];         // 4 KB
  char* sHb = (char*)&sH[0][0];
  const int tid = threadIdx.x;
  const int lane = tid & 63;
  const int wv = tid >> 6;       // 0..7
  const int kt = blockIdx.x;     // one 64-row k-tile per block
  const int r0 = kt * 64;
  const int fr = lane & 15, fq = lane >> 4;

  sW1[tid] = Wa1[tid];
  sW2[tid] = Wa2[tid];

  // staging role: row srow (0..63), k-chunk skc (8 floats)
  const int srow = tid >> 3;
  const int skc = (tid & 7) * 8;
  const float* hp = h + (size_t)(r0 + srow) * KIN + skc;
  const int wby = ((srow * 128 + skc * 2) ^ ((srow & 7) << 4));
  float sp = 0.f, dp = 0.f;

  f32x4 acc[4][2];
#pragma unroll
  for (int mr = 0; mr < 4; ++mr) {
    acc[mr][0] = (f32x4){0.f, 0.f, 0.f, 0.f};
    acc[mr][1] = (f32x4){0.f, 0.f, 0.f, 0.f};
  }
  ushort8_t Bs[2][2];  // [n][kk]

  float hv[8];
  {
    float4 a = *(const float4*)hp;
    float4 b = *(const float4*)(hp + 4);
    hv[0] = a.x; hv[1] = a.y; hv[2] = a.z; hv[3] = a.w;
    hv[4] = b.x; hv[5] = b.y; hv[6] = b.z; hv[7] = b.w;
  }

#pragma unroll 1
  for (int it = 0; it < 8; ++it) {
    __syncthreads();  // sH consumers of previous iter done (also covers sW stage)
    const int kb = it * 64 + skc;
#pragma unroll
    for (int j = 0; j < 8; ++j) {
      sp = fmaf(hv[j], sW1[kb + j], sp);
      dp = fmaf(hv[j], sW2[kb + j], dp);
    }
    uint4 pk;
    pk.x = cvt_pk_bf16(hv[0], hv[1]);
    pk.y = cvt_pk_bf16(hv[2], hv[3]);
    pk.z = cvt_pk_bf16(hv[4], hv[5]);
    pk.w = cvt_pk_bf16(hv[6], hv[7]);
    *(uint4*)(sHb + wby) = pk;
    float hn[8];
    if (it < 7) {
      float4 a = *(const float4*)(hp + (it + 1) * 64);
      float4 b = *(const float4*)(hp + (it + 1) * 64 + 4);
      hn[0] = a.x; hn[1] = a.y; hn[2] = a.z; hn[3] = a.w;
      hn[4] = b.x; hn[5] = b.y; hn[6] = b.z; hn[7] = b.w;
    }
    __syncthreads();  // sH tile ready
#pragma unroll
    for (int n = 0; n < 2; ++n)
#pragma unroll
      for (int kk = 0; kk < 2; ++kk)
        Bs[n][kk] = *(const ushort8_t*)(Wb +
            (((size_t)(it * 2 + kk) * 16 + wv * 2 + n) * 64 + lane) * 8);
#pragma unroll
    for (int mr = 0; mr < 4; ++mr) {
      bf16x8 a0 = __builtin_bit_cast(bf16x8, *(const ushort8_t*)(sHb +
          (((mr * 16 + fr) * 128 + 0 * 64 + fq * 16) ^ ((fr & 7) << 4))));
      bf16x8 a1 = __builtin_bit_cast(bf16x8, *(const ushort8_t*)(sHb +
          (((mr * 16 + fr) * 128 + 1 * 64 + fq * 16) ^ ((fr & 7) << 4))));
      acc[mr][0] = MF(a0, Bs[0][0], acc[mr][0]);
      acc[mr][0] = MF(a1, Bs[0][1], acc[mr][0]);
      acc[mr][1] = MF(a0, Bs[1][0], acc[mr][1]);
      acc[mr][1] = MF(a1, Bs[1][1], acc[mr][1]);
    }
#pragma unroll
    for (int j = 0; j < 8; ++j) hv[j] = hn[j];
  }

  // src/dst reduce across the 8 threads of a row (adjacent lanes)
  sp += __shfl_xor(sp, 1, 8);
  sp += __shfl_xor(sp, 2, 8);
  sp += __shfl_xor(sp, 4, 8);
  dp += __shfl_xor(dp, 1, 8);
  dp += __shfl_xor(dp, 2, 8);
  dp += __shfl_xor(dp, 4, 8);
  if ((tid & 7) == 0) {
    src[r0 + srow] = sp;
    dstv[r0 + srow] = dp;
    atomicMax(Dup, fkey(dp));
  }

  // epilogue: bounce acc -> sBounce (row-major) -> WhF fragment-order direct.
  // pass covers cols [pass*128, pass*128+128): 16 chunks of 1KB, 2 per wave.
#pragma unroll 1
  for (int pass = 0; pass < 2; ++pass) {
    __syncthreads();
    if ((wv >> 2) == pass) {
      const int fbase = (wv & 3) * 32;
#pragma unroll
      for (int mr = 0; mr < 4; ++mr)
#pragma unroll
        for (int n = 0; n < 2; ++n)
#pragma unroll
          for (int r = 0; r < 4; ++r)
            sBounce[mr * 16 + fq * 4 + r][fbase + n * 16 + fr] =
                f2bf(acc[mr][n][r]);
    }
    __syncthreads();
    // gather 2 chunks per wave in B-fragment order (same mapping as old k_trF)
#pragma unroll
    for (int i = 0; i < 2; ++i) {
      const int g = wv * 2 + i;          // 0..15
      const int wloc = g >> 2;           // 0..3
      const int nc = (g >> 1) & 1;
      const int kh = g & 1;
      ushort8_t o;
#pragma unroll
      for (int e = 0; e < 8; ++e)
        o[e] = sBounce[kh * 32 + (lane >> 4) * 8 + e][wloc * 32 + nc * 16 + (lane & 15)];
      const int w = pass * 4 + wloc;
      const size_t idx = ((((size_t)kt * 8 + w) * 2 + nc) * 2 + kh) * 64 + lane;
      *(ushort8_t*)(WhF + idx * 8) = o;
    }
  }
}

// ---- k_attn: R14 optimum (2-slot B, 128x32 consumer tiles, lean prods) ---
struct Bset { ushort8_t b[2][2]; };  // [nc][kh]

#define BAR()                                              \
  {                                                        \
    asm volatile("s_waitcnt lgkmcnt(0)" ::: "memory");     \
    __builtin_amdgcn_s_barrier();                          \
    asm volatile("" ::: "memory");                         \
  }

#define TI(t) (((t) + ph0) & (NT4 - 1))

#define LOADB(BS, ktl)                                                 \
  {                                                                    \
    const unsigned short* p_ = bfw + (size_t)(ktl) * 16384;            \
    BS.b[0][0] = *(const ushort8_t*)(p_);                              \
    BS.b[0][1] = *(const ushort8_t*)(p_ + 512);                        \
    BS.b[1][0] = *(const ushort8_t*)(p_ + 1024);                       \
    BS.b[1][1] = *(const ushort8_t*)(p_ + 1536);                       \
  }

#define WGEN4(AJ, ktl, koff, buf)                                      \
  {                                                                    \
    float4 dv = *(const float4*)&sD[(ktl) * BK + (koff)];              \
    float x0 = s_r + dv.x, x1 = s_r + dv.y;                            \
    float x2 = s_r + dv.z, x3 = s_r + dv.w;                            \
    float w0 = (AJ.x > 0) ? __expf(fmaxf(x0, ALPHA * x0) - c_r) : 0.f; \
    float w1 = (AJ.y > 0) ? __expf(fmaxf(x1, ALPHA * x1) - c_r) : 0.f; \
    float w2 = (AJ.z > 0) ? __expf(fmaxf(x2, ALPHA * x2) - c_r) : 0.f; \
    float w3 = (AJ.w > 0) ? __expf(fmaxf(x3, ALPHA * x3) - c_r) : 0.f; \
    lsum += (w0 + w1) + (w2 + w3);                                     \
    uint2 pk;                                                          \
    pk.x = cvt_pk_bf16(w0, w1);                                        \
    pk.y = cvt_pk_bf16(w2, w3);                                        \
    *(uint2*)(sAb + (buf) * 16384 +                                    \
              ((pr * 128 + (koff) * 2) ^ ((pr & 7) << 4))) = pk;       \
  }

#define WGEN16(A0, A1, A2, A3, ktl, buf)                               \
  {                                                                    \
    WGEN4(A0, ktl, pk16 + 0, buf);                                     \
    WGEN4(A1, ktl, pk16 + 4, buf);                                     \
    WGEN4(A2, ktl, pk16 + 8, buf);                                     \
    WGEN4(A3, ktl, pk16 + 12, buf);                                    \
  }

#define LOADADJ16(A0, A1, A2, A3, ktl)                                 \
  {                                                                    \
    const int4v* ap = (const int4v*)(adjp + (size_t)(ktl) * BK);       \
    A0 = __builtin_nontemporal_load(ap);                               \
    A1 = __builtin_nontemporal_load(ap + 1);                           \
    A2 = __builtin_nontemporal_load(ap + 2);                           \
    A3 = __builtin_nontemporal_load(ap + 3);                           \
  }

#define LDA(cur, mr, kk)                                                        \
  __builtin_bit_cast(bf16x8,                                                    \
    *(const ushort8_t*)(sAb + (cur) * 16384 +                                   \
      ((((mr) * 16 + fr) * 128 + (kk) * 64 + fq * 16) ^ ((fr & 7) << 4))))

#define MSTEP(cur, BS)                                                 \
  {                                                                    \
    _Pragma("unroll")                                                  \
    for (int mr = 0; mr < 8; ++mr) {                                   \
      bf16x8 a0 = LDA(cur, mr, 0), a1 = LDA(cur, mr, 1);               \
      acc[mr][0] = MF(a0, BS.b[0][0], acc[mr][0]);                     \
      acc[mr][0] = MF(a1, BS.b[0][1], acc[mr][0]);                     \
      acc[mr][1] = MF(a0, BS.b[1][0], acc[mr][1]);                     \
      acc[mr][1] = MF(a1, BS.b[1][1], acc[mr][1]);                     \
    }                                                                  \
  }

__global__ __launch_bounds__(1024) void k_attn(const int* __restrict__ adj,
                                               const unsigned short* __restrict__ WhF,
                                               const float* __restrict__ src,
                                               const float* __restrict__ dstv,
                                               const unsigned* __restrict__ Dup,
                                               float* __restrict__ Pbuf,
                                               float* __restrict__ Lsum) {
  __shared__ unsigned short sA[2][ROWS][BK];  // 32 KB dbuf, XOR-swizzled rows
  __shared__ float sD[KQ];                    // 8 KB: this quarter's dstv
  char* sAb = (char*)&sA[0][0][0];
  const int tid = threadIdx.x;
  const int lane = tid & 63;
  const int wave = tid >> 6;      // 0..7 consumers, 8..15 producers
  const int qtr = blockIdx.x & 3;
  const int rg = blockIdx.x >> 2;
  const int r0 = rg * ROWS;
  const int ph0 = rg & (NT4 - 1);
  const int kbase = qtr * KQ;
  const float D = funkey(*Dup);

  *(float2*)&sD[tid * 2] = *(const float2*)(dstv + kbase + tid * 2);
  __syncthreads();

  // ---------- producer state (waves 8..15): 4 threads per row ----------
  const int ptid = tid - 512;
  const int pr = ptid >> 2;
  const int pk16 = (ptid & 3) * 16;
  const float s_r = src[r0 + pr];
  const float c_r = lrelu(s_r + D);
  const int* adjp = adj + (size_t)(r0 + pr) * NN + kbase + pk16;
  float lsum = 0.f;

  // ---------- consumer state (waves 0..7): wave tile 128x32 ----------
  const int fr = lane & 15;
  const int fq = lane >> 4;
  const unsigned short* bfw =
      WhF + ((size_t)(qtr * NT4) * 8 + wave) * 2048 + lane * 8;
  f32x4 acc[8][2];
#pragma unroll
  for (int mr = 0; mr < 8; ++mr) {
    acc[mr][0] = (f32x4){0.f, 0.f, 0.f, 0.f};
    acc[mr][1] = (f32x4){0.f, 0.f, 0.f, 0.f};
  }
  Bset B0, B1;
  int4v aA0, aA1, aA2, aA3;
  int4v aB0, aB1, aB2, aB3;

  // ---------- prologue ----------
  if (wave >= 8) {
    int4v d0, d1, d2, d3;
    {
      const int4v* ap = (const int4v*)(adjp + (size_t)TI(0) * BK);
      d0 = ap[0]; d1 = ap[1]; d2 = ap[2]; d3 = ap[3];
    }
    WGEN16(d0, d1, d2, d3, TI(0), 0);
    LOADADJ16(aB0, aB1, aB2, aB3, TI(1));
    LOADADJ16(aA0, aA1, aA2, aA3, TI(2));
  } else {
    LOADB(B0, TI(0));
    LOADB(B1, TI(1));
  }
  BAR();

  // ---------- main loop ----------
  if (wave < 8) {
#pragma unroll 1
    for (int p = 0; p < NT4; p += 2) {
      { MSTEP(0, B0); LOADB(B0, TI(p + 2)); BAR(); }
      { MSTEP(1, B1); LOADB(B1, TI(p + 3)); BAR(); }
    }
#pragma unroll
    for (int mr = 0; mr < 8; ++mr) {
#pragma unroll
      for (int r = 0; r < 4; ++r) {
        const int row = mr * 16 + fq * 4 + r;
#pragma unroll
        for (int nc = 0; nc < 2; ++nc) {
          const int col = wave * 32 + nc * 16 + fr;
          Pbuf[(size_t)(qtr * NN + r0 + row) * KOUT + col] = acc[mr][nc][r];
        }
      }
    }
  } else {
#pragma unroll 1
    for (int p = 0; p < NT4; p += 2) {
      {
        WGEN16(aB0, aB1, aB2, aB3, TI(p + 1), 1);
        LOADADJ16(aB0, aB1, aB2, aB3, TI(p + 3));
        BAR();
      }
      {
        if (p + 2 < NT4) { WGEN16(aA0, aA1, aA2, aA3, TI(p + 2), 0); }
        LOADADJ16(aA0, aA1, aA2, aA3, TI(p + 4));
        BAR();
      }
    }
    lsum += __shfl_xor(lsum, 1, 4);
    lsum += __shfl_xor(lsum, 2, 4);
    if ((ptid & 3) == 0) Lsum[qtr * NN + r0 + pr] = lsum;
  }
}

// ---------------- k_comb: out = elu(sum(P)/sum(L)) -----------------------
__global__ __launch_bounds__(256) void k_comb(const float* __restrict__ Pbuf,
                                              const float* __restrict__ Lsum,
                                              float* __restrict__ out) {
  const int t = threadIdx.x;
  const int row = blockIdx.x * 4 + (t >> 6);
  const int col = (t & 63) * 4;
  const float l = Lsum[row] + Lsum[NN + row] + Lsum[2 * NN + row] + Lsum[3 * NN + row];
  float4 p0 = *(const float4*)(Pbuf + (size_t)row * KOUT + col);
  float4 p1 = *(const float4*)(Pbuf + (size_t)(NN + row) * KOUT + col);
  float4 p2 = *(const float4*)(Pbuf + (size_t)(2 * NN + row) * KOUT + col);
  float4 p3 = *(const float4*)(Pbuf + (size_t)(3 * NN + row) * KOUT + col);
  float4 v;
  v.x = (p0.x + p1.x + p2.x + p3.x) / l;
  v.y = (p0.y + p1.y + p2.y + p3.y) / l;
  v.z = (p0.z + p1.z + p2.z + p3.z) / l;
  v.w = (p0.w + p1.w + p2.w + p3.w) / l;
  v.x = v.x > 0.f ? v.x : __expf(v.x) - 1.f;
  v.y = v.y > 0.f ? v.y : __expf(v.y) - 1.f;
  v.z = v.z > 0.f ? v.z : __expf(v.z) - 1.f;
  v.w = v.w > 0.f ? v.w : __expf(v.w) - 1.f;
  *(float4*)(out + (size_t)row * KOUT + col) = v;
}

extern "C" void kernel_launch(void* const* d_in, const int* in_sizes, int n_in,
                              void* d_out, int out_size, void* d_ws, size_t ws_size,
                              hipStream_t stream) {
  const float* h = (const float*)d_in[0];
  const int* adj = (const int*)d_in[1];
  const float* W = (const float*)d_in[2];
  const float* a1 = (const float*)d_in[3];
  const float* a2 = (const float*)d_in[4];
  float* out = (float*)d_out;

  unsigned short* WhF = (unsigned short*)d_ws;            // 4 MB (fragment order)
  float* src = (float*)(WhF + (size_t)NN * KOUT);         // 32 KB
  float* dstv = src + NN;                                 // 32 KB
  unsigned* Dup = (unsigned*)(dstv + NN);                 // pad 16
  float* Pbuf = (float*)(Dup + 16);                       // 32 MB partials
  float* Lsum = Pbuf + (size_t)4 * NN * KOUT;             // 128 KB
  unsigned short* Wb = (unsigned short*)(Lsum + 4 * NN);  // 256 KB frag W
  float* Wa1 = (float*)(Wb + (size_t)KIN * KOUT);         // 2 KB
  float* Wa2 = Wa1 + KIN;                                 // 2 KB

  hipLaunchKernelGGL(k_wa, dim3(2), dim3(256), 0, stream, W, a1, a2, Wa1, Wa2, Dup);
  hipLaunchKernelGGL(k_prep, dim3(256), dim3(64), 0, stream, W, Wb);
  hipLaunchKernelGGL(k_wh2, dim3(NN / 64), dim3(512), 0, stream,
                     h, Wb, Wa1, Wa2, WhF, src, dstv, Dup);
  hipLaunchKernelGGL(k_attn, dim3(256), dim3(1024), 0, stream,
                     adj, WhF, src, dstv, Dup, Pbuf, Lsum);
  hipLaunchKernelGGL(k_comb, dim3(NN / 4), dim3(256), 0, stream, Pbuf, Lsum, out);
}

// Round 18
// 128.421 us; speedup vs baseline: 1.5085x; 1.0579x over previous
//
#include <hip/hip_runtime.h>
#include <hip/hip_bf16.h>

#define NN 8192
#define KIN 512
#define KOUT 256
#define ALPHA 0.2f
#define BK 64
#define ROWS 128        // rows per block (k_attn)
#define KQ (NN / 4)     // k-range per quarter
#define NT4 (KQ / BK)   // 32 k-tiles per quarter

typedef __bf16 bf16x8 __attribute__((ext_vector_type(8)));
typedef float f32x4 __attribute__((ext_vector_type(4)));
typedef unsigned short ushort8_t __attribute__((ext_vector_type(8)));
typedef unsigned short ushort4_t __attribute__((ext_vector_type(4)));
typedef int int4v __attribute__((ext_vector_type(4)));

__device__ __forceinline__ float lrelu(float x) { return x > 0.f ? x : ALPHA * x; }

__device__ __forceinline__ unsigned short f2bf(float f) {
  union { float f; unsigned u; } v; v.f = f;
  unsigned r = v.u + 0x7fffu + ((v.u >> 16) & 1u);  // RNE to bf16
  return (unsigned short)(r >> 16);
}
__device__ __forceinline__ float bf2f(unsigned short b) {
  union { unsigned u; float f; } v; v.u = ((unsigned)b) << 16;
  return v.f;
}

// pack two f32 -> one u32 of 2x bf16 (RNE) via HW instruction
__device__ __forceinline__ unsigned cvt_pk_bf16(float lo, float hi) {
  unsigned r;
  asm("v_cvt_pk_bf16_f32 %0, %1, %2" : "=v"(r) : "v"(lo), "v"(hi));
  return r;
}

// monotone float->uint key for atomicMax
__device__ __forceinline__ unsigned fkey(float x) {
  unsigned b = __float_as_uint(x);
  return (b & 0x80000000u) ? ~b : (b | 0x80000000u);
}
__device__ __forceinline__ float funkey(unsigned k) {
  unsigned b = (k & 0x80000000u) ? (k ^ 0x80000000u) : ~k;
  return __uint_as_float(b);
}

#define MF(a, b, c) __builtin_amdgcn_mfma_f32_16x16x32_bf16(a, b, c, 0, 0, 0)

// ---- k_wp: merged prep. blocks 0..63: W -> Wb (frag order); 64,65: Wa1/Wa2 -
__global__ __launch_bounds__(256) void k_wp(const float* __restrict__ W,
                                            const float* __restrict__ a1,
                                            const float* __restrict__ a2,
                                            unsigned short* __restrict__ Wb,
                                            float* __restrict__ Wa1,
                                            float* __restrict__ Wa2,
                                            unsigned* __restrict__ Dup) {
  const int blk = blockIdx.x;
  const int tid = threadIdx.x;
  if (blk < 64) {
    // fragment-order bf16 W: 4 frag-blocks per block
    const int b = blk * 4 + (tid >> 6);   // 0..255 = kt*16 + cg
    const int kt = b >> 4, cg = b & 15;
    const int l = tid & 63;
    const int krow = kt * 32 + (l >> 4) * 8;
    const int col = cg * 16 + (l & 15);
    ushort8_t o;
#pragma unroll
    for (int e = 0; e < 8; ++e) o[e] = f2bf(W[(size_t)(krow + e) * KOUT + col]);
    *(ushort8_t*)(Wb + ((size_t)b * 64 + l) * 8) = o;
  } else {
    const int k = (blk - 64) * 256 + tid;  // 0..511
    float s1 = 0.f, s2 = 0.f;
    const float* wr = W + (size_t)k * KOUT;
    for (int c = 0; c < KOUT; c += 4) {
      float4 w4 = *(const float4*)(wr + c);
      float4 b1 = *(const float4*)(a1 + c);
      float4 b2 = *(const float4*)(a2 + c);
      s1 += w4.x * b1.x + w4.y * b1.y + w4.z * b1.z + w4.w * b1.w;
      s2 += w4.x * b2.x + w4.y * b2.y + w4.z * b2.z + w4.w * b2.w;
    }
    Wa1[k] = s1;
    Wa2[k] = s2;
    if (k == 0) *Dup = 0u;  // key(x) > 0 for any real float
  }
}

// -------- k_wh2: Wh = h @ W via MFMA; writes WhF fragment-order direct -----
// grid 128 blocks x 512 thr (8 waves); M-tile 64 (= one kt), wave out 64x32
__global__ __launch_bounds__(512) void k_wh2(const float* __restrict__ h,
                                             const unsigned short* __restrict__ Wb,
                                             const float* __restrict__ Wa1,
                                             const float* __restrict__ Wa2,
                                             unsigned short* __restrict__ WhF,
                                             float* __restrict__ src,
                                             float* __restrict__ dstv,
                                             unsigned* __restrict__ Dup) {
  __shared__ unsigned short sH[64][64];        // 8 KB, XOR-swizzled rows
  __shared__ unsigned short sBounce[64][132];  // 16.5 KB epilogue bounce (padded)
  __shared__ float sW1[KIN], sW2[KIN];         // 4 KB
  char* sHb = (char*)&sH[0][0];
  const int tid = threadIdx.x;
  const int lane = tid & 63;
  const int wv = tid >> 6;       // 0..7
  const int kt = blockIdx.x;     // one 64-row k-tile per block
  const int r0 = kt * 64;
  const int fr = lane & 15, fq = lane >> 4;

  sW1[tid] = Wa1[tid];
  sW2[tid] = Wa2[tid];

  // staging role: row srow (0..63), k-chunk skc (8 floats)
  const int srow = tid >> 3;
  const int skc = (tid & 7) * 8;
  const float* hp = h + (size_t)(r0 + srow) * KIN + skc;
  const int wby = ((srow * 128 + skc * 2) ^ ((srow & 7) << 4));
  float sp = 0.f, dp = 0.f;

  f32x4 acc[4][2];
#pragma unroll
  for (int mr = 0; mr < 4; ++mr) {
    acc[mr][0] = (f32x4){0.f, 0.f, 0.f, 0.f};
    acc[mr][1] = (f32x4){0.f, 0.f, 0.f, 0.f};
  }
  ushort8_t Bs[2][2];  // [n][kk]

  float hv[8];
  {
    float4 a = *(const float4*)hp;
    float4 b = *(const float4*)(hp + 4);
    hv[0] = a.x; hv[1] = a.y; hv[2] = a.z; hv[3] = a.w;
    hv[4] = b.x; hv[5] = b.y; hv[6] = b.z; hv[7] = b.w;
  }

#pragma unroll 1
  for (int it = 0; it < 8; ++it) {
    __syncthreads();  // sH consumers of previous iter done (also covers sW stage)
    const int kb = it * 64 + skc;
#pragma unroll
    for (int j = 0; j < 8; ++j) {
      sp = fmaf(hv[j], sW1[kb + j], sp);
      dp = fmaf(hv[j], sW2[kb + j], dp);
    }
    uint4 pk;
    pk.x = cvt_pk_bf16(hv[0], hv[1]);
    pk.y = cvt_pk_bf16(hv[2], hv[3]);
    pk.z = cvt_pk_bf16(hv[4], hv[5]);
    pk.w = cvt_pk_bf16(hv[6], hv[7]);
    *(uint4*)(sHb + wby) = pk;
    float hn[8];
    if (it < 7) {
      float4 a = *(const float4*)(hp + (it + 1) * 64);
      float4 b = *(const float4*)(hp + (it + 1) * 64 + 4);
      hn[0] = a.x; hn[1] = a.y; hn[2] = a.z; hn[3] = a.w;
      hn[4] = b.x; hn[5] = b.y; hn[6] = b.z; hn[7] = b.w;
    }
    __syncthreads();  // sH tile ready
#pragma unroll
    for (int n = 0; n < 2; ++n)
#pragma unroll
      for (int kk = 0; kk < 2; ++kk)
        Bs[n][kk] = *(const ushort8_t*)(Wb +
            (((size_t)(it * 2 + kk) * 16 + wv * 2 + n) * 64 + lane) * 8);
#pragma unroll
    for (int mr = 0; mr < 4; ++mr) {
      bf16x8 a0 = __builtin_bit_cast(bf16x8, *(const ushort8_t*)(sHb +
          (((mr * 16 + fr) * 128 + 0 * 64 + fq * 16) ^ ((fr & 7) << 4))));
      bf16x8 a1 = __builtin_bit_cast(bf16x8, *(const ushort8_t*)(sHb +
          (((mr * 16 + fr) * 128 + 1 * 64 + fq * 16) ^ ((fr & 7) << 4))));
      acc[mr][0] = MF(a0, Bs[0][0], acc[mr][0]);
      acc[mr][0] = MF(a1, Bs[0][1], acc[mr][0]);
      acc[mr][1] = MF(a0, Bs[1][0], acc[mr][1]);
      acc[mr][1] = MF(a1, Bs[1][1], acc[mr][1]);
    }
#pragma unroll
    for (int j = 0; j < 8; ++j) hv[j] = hn[j];
  }

  // src/dst reduce across the 8 threads of a row (adjacent lanes)
  sp += __shfl_xor(sp, 1, 8);
  sp += __shfl_xor(sp, 2, 8);
  sp += __shfl_xor(sp, 4, 8);
  dp += __shfl_xor(dp, 1, 8);
  dp += __shfl_xor(dp, 2, 8);
  dp += __shfl_xor(dp, 4, 8);
  if ((tid & 7) == 0) {
    src[r0 + srow] = sp;
    dstv[r0 + srow] = dp;
    atomicMax(Dup, fkey(dp));
  }

  // epilogue: bounce acc -> sBounce (row-major) -> WhF fragment-order direct.
#pragma unroll 1
  for (int pass = 0; pass < 2; ++pass) {
    __syncthreads();
    if ((wv >> 2) == pass) {
      const int fbase = (wv & 3) * 32;
#pragma unroll
      for (int mr = 0; mr < 4; ++mr)
#pragma unroll
        for (int n = 0; n < 2; ++n)
#pragma unroll
          for (int r = 0; r < 4; ++r)
            sBounce[mr * 16 + fq * 4 + r][fbase + n * 16 + fr] =
                f2bf(acc[mr][n][r]);
    }
    __syncthreads();
#pragma unroll
    for (int i = 0; i < 2; ++i) {
      const int g = wv * 2 + i;          // 0..15
      const int wloc = g >> 2;           // 0..3
      const int nc = (g >> 1) & 1;
      const int kh = g & 1;
      ushort8_t o;
#pragma unroll
      for (int e = 0; e < 8; ++e)
        o[e] = sBounce[kh * 32 + (lane >> 4) * 8 + e][wloc * 32 + nc * 16 + (lane & 15)];
      const int w = pass * 4 + wloc;
      const size_t idx = ((((size_t)kt * 8 + w) * 2 + nc) * 2 + kh) * 64 + lane;
      *(ushort8_t*)(WhF + idx * 8) = o;
    }
  }
}

// ---- k_attn: R14 optimum (2-slot B, 128x32 consumer tiles, lean prods) ---
struct Bset { ushort8_t b[2][2]; };  // [nc][kh]

#define BAR()                                              \
  {                                                        \
    asm volatile("s_waitcnt lgkmcnt(0)" ::: "memory");     \
    __builtin_amdgcn_s_barrier();                          \
    asm volatile("" ::: "memory");                         \
  }

#define TI(t) (((t) + ph0) & (NT4 - 1))

#define LOADB(BS, ktl)                                                 \
  {                                                                    \
    const unsigned short* p_ = bfw + (size_t)(ktl) * 16384;            \
    BS.b[0][0] = *(const ushort8_t*)(p_);                              \
    BS.b[0][1] = *(const ushort8_t*)(p_ + 512);                        \
    BS.b[1][0] = *(const ushort8_t*)(p_ + 1024);                       \
    BS.b[1][1] = *(const ushort8_t*)(p_ + 1536);                       \
  }

#define WGEN4(AJ, ktl, koff, buf)                                      \
  {                                                                    \
    float4 dv = *(const float4*)&sD[(ktl) * BK + (koff)];              \
    float x0 = s_r + dv.x, x1 = s_r + dv.y;                            \
    float x2 = s_r + dv.z, x3 = s_r + dv.w;                            \
    float w0 = (AJ.x > 0) ? __expf(fmaxf(x0, ALPHA * x0) - c_r) : 0.f; \
    float w1 = (AJ.y > 0) ? __expf(fmaxf(x1, ALPHA * x1) - c_r) : 0.f; \
    float w2 = (AJ.z > 0) ? __expf(fmaxf(x2, ALPHA * x2) - c_r) : 0.f; \
    float w3 = (AJ.w > 0) ? __expf(fmaxf(x3, ALPHA * x3) - c_r) : 0.f; \
    lsum += (w0 + w1) + (w2 + w3);                                     \
    uint2 pk;                                                          \
    pk.x = cvt_pk_bf16(w0, w1);                                        \
    pk.y = cvt_pk_bf16(w2, w3);                                        \
    *(uint2*)(sAb + (buf) * 16384 +                                    \
              ((pr * 128 + (koff) * 2) ^ ((pr & 7) << 4))) = pk;       \
  }

#define WGEN16(A0, A1, A2, A3, ktl, buf)                               \
  {                                                                    \
    WGEN4(A0, ktl, pk16 + 0, buf);                                     \
    WGEN4(A1, ktl, pk16 + 4, buf);                                     \
    WGEN4(A2, ktl, pk16 + 8, buf);                                     \
    WGEN4(A3, ktl, pk16 + 12, buf);                                    \
  }

#define LOADADJ16(A0, A1, A2, A3, ktl)                                 \
  {                                                                    \
    const int4v* ap = (const int4v*)(adjp + (size_t)(ktl) * BK);       \
    A0 = __builtin_nontemporal_load(ap);                               \
    A1 = __builtin_nontemporal_load(ap + 1);                           \
    A2 = __builtin_nontemporal_load(ap + 2);                           \
    A3 = __builtin_nontemporal_load(ap + 3);                           \
  }

#define LDA(cur, mr, kk)                                                        \
  __builtin_bit_cast(bf16x8,                                                    \
    *(const ushort8_t*)(sAb + (cur) * 16384 +                                   \
      ((((mr) * 16 + fr) * 128 + (kk) * 64 + fq * 16) ^ ((fr & 7) << 4))))

#define MSTEP(cur, BS)                                                 \
  {                                                                    \
    _Pragma("unroll")                                                  \
    for (int mr = 0; mr < 8; ++mr) {                                   \
      bf16x8 a0 = LDA(cur, mr, 0), a1 = LDA(cur, mr, 1);               \
      acc[mr][0] = MF(a0, BS.b[0][0], acc[mr][0]);                     \
      acc[mr][0] = MF(a1, BS.b[0][1], acc[mr][0]);                     \
      acc[mr][1] = MF(a0, BS.b[1][0], acc[mr][1]);                     \
      acc[mr][1] = MF(a1, BS.b[1][1], acc[mr][1]);                     \
    }                                                                  \
  }

__global__ __launch_bounds__(1024) void k_attn(const int* __restrict__ adj,
                                               const unsigned short* __restrict__ WhF,
                                               const float* __restrict__ src,
                                               const float* __restrict__ dstv,
                                               const unsigned* __restrict__ Dup,
                                               unsigned short* __restrict__ Pb16,
                                               float* __restrict__ Lsum) {
  __shared__ unsigned short sA[2][ROWS][BK];  // 32 KB dbuf, XOR-swizzled rows
  __shared__ float sD[KQ];                    // 8 KB: this quarter's dstv
  char* sAb = (char*)&sA[0][0][0];
  const int tid = threadIdx.x;
  const int lane = tid & 63;
  const int wave = tid >> 6;      // 0..7 consumers, 8..15 producers
  const int qtr = blockIdx.x & 3;
  const int rg = blockIdx.x >> 2;
  const int r0 = rg * ROWS;
  const int ph0 = rg & (NT4 - 1);
  const int kbase = qtr * KQ;
  const float D = funkey(*Dup);

  *(float2*)&sD[tid * 2] = *(const float2*)(dstv + kbase + tid * 2);
  __syncthreads();

  // ---------- producer state (waves 8..15): 4 threads per row ----------
  const int ptid = tid - 512;
  const int pr = ptid >> 2;
  const int pk16 = (ptid & 3) * 16;
  const float s_r = src[r0 + pr];
  const float c_r = lrelu(s_r + D);
  const int* adjp = adj + (size_t)(r0 + pr) * NN + kbase + pk16;
  float lsum = 0.f;

  // ---------- consumer state (waves 0..7): wave tile 128x32 ----------
  const int fr = lane & 15;
  const int fq = lane >> 4;
  const unsigned short* bfw =
      WhF + ((size_t)(qtr * NT4) * 8 + wave) * 2048 + lane * 8;
  f32x4 acc[8][2];
#pragma unroll
  for (int mr = 0; mr < 8; ++mr) {
    acc[mr][0] = (f32x4){0.f, 0.f, 0.f, 0.f};
    acc[mr][1] = (f32x4){0.f, 0.f, 0.f, 0.f};
  }
  Bset B0, B1;
  int4v aA0, aA1, aA2, aA3;
  int4v aB0, aB1, aB2, aB3;

  // ---------- prologue ----------
  if (wave >= 8) {
    int4v d0, d1, d2, d3;
    {
      const int4v* ap = (const int4v*)(adjp + (size_t)TI(0) * BK);
      d0 = ap[0]; d1 = ap[1]; d2 = ap[2]; d3 = ap[3];
    }
    WGEN16(d0, d1, d2, d3, TI(0), 0);
    LOADADJ16(aB0, aB1, aB2, aB3, TI(1));
    LOADADJ16(aA0, aA1, aA2, aA3, TI(2));
  } else {
    LOADB(B0, TI(0));
    LOADB(B1, TI(1));
  }
  BAR();

  // ---------- main loop ----------
  if (wave < 8) {
#pragma unroll 1
    for (int p = 0; p < NT4; p += 2) {
      { MSTEP(0, B0); LOADB(B0, TI(p + 2)); BAR(); }
      { MSTEP(1, B1); LOADB(B1, TI(p + 3)); BAR(); }
    }
    // store bf16 partial accumulators
#pragma unroll
    for (int mr = 0; mr < 8; ++mr) {
#pragma unroll
      for (int r = 0; r < 4; ++r) {
        const int row = mr * 16 + fq * 4 + r;
#pragma unroll
        for (int nc = 0; nc < 2; ++nc) {
          const int col = wave * 32 + nc * 16 + fr;
          Pb16[(size_t)(qtr * NN + r0 + row) * KOUT + col] = f2bf(acc[mr][nc][r]);
        }
      }
    }
  } else {
#pragma unroll 1
    for (int p = 0; p < NT4; p += 2) {
      {
        WGEN16(aB0, aB1, aB2, aB3, TI(p + 1), 1);
        LOADADJ16(aB0, aB1, aB2, aB3, TI(p + 3));
        BAR();
      }
      {
        if (p + 2 < NT4) { WGEN16(aA0, aA1, aA2, aA3, TI(p + 2), 0); }
        LOADADJ16(aA0, aA1, aA2, aA3, TI(p + 4));
        BAR();
      }
    }
    lsum += __shfl_xor(lsum, 1, 4);
    lsum += __shfl_xor(lsum, 2, 4);
    if ((ptid & 3) == 0) Lsum[qtr * NN + r0 + pr] = lsum;
  }
}

// ---------------- k_comb: out = elu(sum(P)/sum(L)) -----------------------
__global__ __launch_bounds__(256) void k_comb(const unsigned short* __restrict__ Pb16,
                                              const float* __restrict__ Lsum,
                                              float* __restrict__ out) {
  const int t = threadIdx.x;
  const int row = blockIdx.x * 4 + (t >> 6);
  const int col = (t & 63) * 4;
  const float l = Lsum[row] + Lsum[NN + row] + Lsum[2 * NN + row] + Lsum[3 * NN + row];
  float s0 = 0.f, s1 = 0.f, s2 = 0.f, s3 = 0.f;
#pragma unroll
  for (int q = 0; q < 4; ++q) {
    ushort4_t p = *(const ushort4_t*)(Pb16 + (size_t)(q * NN + row) * KOUT + col);
    s0 += bf2f(p[0]);
    s1 += bf2f(p[1]);
    s2 += bf2f(p[2]);
    s3 += bf2f(p[3]);
  }
  float4 v;
  v.x = s0 / l;
  v.y = s1 / l;
  v.z = s2 / l;
  v.w = s3 / l;
  v.x = v.x > 0.f ? v.x : __expf(v.x) - 1.f;
  v.y = v.y > 0.f ? v.y : __expf(v.y) - 1.f;
  v.z = v.z > 0.f ? v.z : __expf(v.z) - 1.f;
  v.w = v.w > 0.f ? v.w : __expf(v.w) - 1.f;
  *(float4*)(out + (size_t)row * KOUT + col) = v;
}

extern "C" void kernel_launch(void* const* d_in, const int* in_sizes, int n_in,
                              void* d_out, int out_size, void* d_ws, size_t ws_size,
                              hipStream_t stream) {
  const float* h = (const float*)d_in[0];
  const int* adj = (const int*)d_in[1];
  const float* W = (const float*)d_in[2];
  const float* a1 = (const float*)d_in[3];
  const float* a2 = (const float*)d_in[4];
  float* out = (float*)d_out;

  unsigned short* WhF = (unsigned short*)d_ws;            // 4 MB (fragment order)
  float* src = (float*)(WhF + (size_t)NN * KOUT);         // 32 KB
  float* dstv = src + NN;                                 // 32 KB
  unsigned* Dup = (unsigned*)(dstv + NN);                 // pad 16
  unsigned short* Pb16 = (unsigned short*)(Dup + 16);     // 16 MB bf16 partials
  float* Lsum = (float*)(Pb16 + (size_t)4 * NN * KOUT);   // 128 KB
  unsigned short* Wb = (unsigned short*)(Lsum + 4 * NN);  // 256 KB frag W
  float* Wa1 = (float*)(Wb + (size_t)KIN * KOUT);         // 2 KB
  float* Wa2 = Wa1 + KIN;                                 // 2 KB

  hipLaunchKernelGGL(k_wp, dim3(66), dim3(256), 0, stream, W, a1, a2, Wb, Wa1, Wa2, Dup);
  hipLaunchKernelGGL(k_wh2, dim3(NN / 64), dim3(512), 0, stream,
                     h, Wb, Wa1, Wa2, WhF, src, dstv, Dup);
  hipLaunchKernelGGL(k_attn, dim3(256), dim3(1024), 0, stream,
                     adj, WhF, src, dstv, Dup, Pb16, Lsum);
  hipLaunchKernelGGL(k_comb, dim3(NN / 4), dim3(256), 0, stream, Pb16, Lsum, out);
}